// Round 10
// baseline (310.653 us; speedup 1.0000x reference)
//
#include <hip/hip_runtime.h>

// LIF layer: B=64, T=256, P=1024, D=1024. reference ignores prv_voltage.
// d_out = [voltage (B*T*D fp32) | spikes (B*T*D fp32)].
//
// R10 correctness theory: np ref = BLAS sgemm; the persistent single
// spike-flip is caused by K-panel association in the currents. Untested
// highest-mass split: KC=512 -> panels [512,512], P0+P1 in f32.
// Covers: OpenBLAS Q>=512 targets (1024=2Q, no tail-halving), AOCL-BLIS
// zen4/5 (KC=512, plain chunking), MKL-512-class, Eigen kc=512 (jax-CPU).
// Within-panel: strict-ascending k, single accumulator (all BLAS
// microkernels); binary spikes make zero-skipping + FMA bitwise-neutral.
// Scan: f32, separate mul/add (numpy ufuncs never contract), >=1.0,
// reset-to-zero, voltage = pre-reset v_new.
// Refuted so far (all bitwise-identical single-flip 0.89453125):
//   asc-f32+f32scan, f64+f64scan, asc-f32+FMAscan, asc-f32+f64scan,
//   panels [384,384,256], [320,320,192,192], [384,320,320], [256x4].

#define LIF_B 64
#define LIF_T 256
#define LIF_P 1024
#define LIF_D 1024
#define LIF_N ((size_t)LIF_B * LIF_T * LIF_D)

__global__ __launch_bounds__(256) void lif_currents_kernel(
    const float* __restrict__ spikes,   // (B*T, P)
    const float* __restrict__ W,        // (P, D)
    float* __restrict__ cur_out)        // (B*T, D) — voltage region of d_out
{
    const int row  = blockIdx.x;          // 0 .. B*T-1
    const int lane = threadIdx.x & 63;
    const int wave = threadIdx.x >> 6;    // 4 waves x 256 d-columns
    const int dbase = wave << 8;

    const float* srow = spikes + (size_t)row * LIF_P;
    const float* wcol = W + dbase + (lane << 2);   // this lane's 4 columns

    // Two K-panels: p in [0,512), [512,1024)   (64-chunk groups: 8, 8)
    float a0x=0.f,a0y=0.f,a0z=0.f,a0w=0.f;
    float a1x=0.f,a1y=0.f,a1z=0.f,a1w=0.f;

    #define LIF_PANEL(J0, J1, AX, AY, AZ, AW)                                   \
    for (int j = (J0); j < (J1); ++j) {                                         \
        const float sv = srow[(j << 6) + lane];                                 \
        unsigned long long m = __ballot(sv != 0.0f);                            \
        const int pbase = j << 6;                                               \
        while (m) {                                                             \
            const int p = pbase + __builtin_ctzll(m);                           \
            m &= (m - 1);                                                       \
            const float4 wv =                                                   \
                *reinterpret_cast<const float4*>(wcol + ((size_t)p << 10));     \
            AX = __fadd_rn(AX, wv.x); AY = __fadd_rn(AY, wv.y);                 \
            AZ = __fadd_rn(AZ, wv.z); AW = __fadd_rn(AW, wv.w);                 \
        }                                                                       \
    }

    LIF_PANEL(0, 8,   a0x, a0y, a0z, a0w)   // p in [0, 512)
    LIF_PANEL(8, 16,  a1x, a1y, a1z, a1w)   // p in [512, 1024)
    #undef LIF_PANEL

    // Panel association: P0 + P1, plain f32 add.
    float4 c;
    c.x = __fadd_rn(a0x, a1x);
    c.y = __fadd_rn(a0y, a1y);
    c.z = __fadd_rn(a0z, a1z);
    c.w = __fadd_rn(a0w, a1w);

    *reinterpret_cast<float4*>(cur_out + (size_t)row * LIF_D + dbase + (lane << 2)) = c;
}

__global__ __launch_bounds__(256) void lif_scan_kernel(
    float* __restrict__ voltage,        // in: staged currents, out: v_new
    float* __restrict__ spikes_out)     // out: binary spikes
{
    const int tid = blockIdx.x * 256 + threadIdx.x;   // 0 .. B*D-1
    const int b = tid >> 10;
    const int d = tid & (LIF_D - 1);

    float v = 0.0f;
    const size_t base = ((size_t)b * LIF_T) * LIF_D + d;

    for (int t = 0; t < LIF_T; ++t) {
        const size_t idx = base + (size_t)t * LIF_D;
        const float cur = voltage[idx];                     // staged current
        // numpy scan: separate f32 mul then add (no FMA contraction)
        const float vn = __fadd_rn(__fmul_rn(0.9f, v), cur);
        const bool fired = (vn >= 1.0f);
        voltage[idx]    = vn;                               // pre-reset voltage
        spikes_out[idx] = fired ? 1.0f : 0.0f;
        v = fired ? 0.0f : vn;                              // reset-to-zero
    }
}

extern "C" void kernel_launch(void* const* d_in, const int* in_sizes, int n_in,
                              void* d_out, int out_size, void* d_ws, size_t ws_size,
                              hipStream_t stream) {
    (void)in_sizes; (void)n_in; (void)out_size; (void)d_ws; (void)ws_size;

    // d_in[0] = prv_voltage (UNUSED by reference)
    const float* spikes = (const float*)d_in[1];   // (B,T,P) binary fp32
    const float* W      = (const float*)d_in[2];   // (P,D) fp32

    float* out        = (float*)d_out;
    float* voltage    = out;                       // N floats (stages currents)
    float* spikes_out = out + LIF_N;               // N floats

    lif_currents_kernel<<<LIF_B * LIF_T, 256, 0, stream>>>(spikes, W, voltage);
    lif_scan_kernel<<<(LIF_B * LIF_D) / 256, 256, 0, stream>>>(voltage, spikes_out);
}